// Round 11
// baseline (145.255 us; speedup 1.0000x reference)
//
#include <hip/hip_runtime.h>
#include <math.h>

// Problem constants (SelfAttention: b=2, d=1024, s=2048, h=16, hd=64)
#define B_  2
#define D_  1024
#define S_  2048
#define H_  16
#define HD_ 64
#define D3_ 3072
#define M_  4096   // B_*S_

typedef __attribute__((ext_vector_type(8))) short short8;
typedef __attribute__((ext_vector_type(4))) float float4v;

__device__ __forceinline__ short f2bf(float f) {
    unsigned u = __builtin_bit_cast(unsigned, f);
    unsigned r = (u + 0x7FFFu + ((u >> 16) & 1u)) >> 16;   // RNE
    return (short)r;
}

__device__ __forceinline__ unsigned cvt_pk_bf16(float lo, float hi) {
    unsigned r;
    asm("v_cvt_pk_bf16_f32 %0, %1, %2" : "=v"(r) : "v"(lo), "v"(hi));
    return r;
}

__device__ __forceinline__ float fast_exp2(float x) {
    float r;
    asm("v_exp_f32 %0, %1" : "=v"(r) : "v"(x));
    return r;
}

#define GLD16(gsrc, ldst)                                                      \
    __builtin_amdgcn_global_load_lds(                                          \
        (const __attribute__((address_space(1))) void*)(gsrc),                 \
        (__attribute__((address_space(3))) void*)(ldst), 16, 0, 0)

// ---------- transpose + fp32->bf16 convert: out[z][c][r] = bf16(in[z][r][c]) ----
__global__ __launch_bounds__(256) void transpose_cvt(const float* __restrict__ in,
                                                     short* __restrict__ out,
                                                     int R, int C) {
    __shared__ float t[32][33];
    const int c0 = blockIdx.x * 32, r0 = blockIdx.y * 32;
    const float* inb = in + (size_t)blockIdx.z * R * C;
    short* outb = out + (size_t)blockIdx.z * R * C;
    const int tx = threadIdx.x, ty = threadIdx.y;
    #pragma unroll
    for (int i = ty; i < 32; i += 8)
        t[i][tx] = inb[(size_t)(r0 + i) * C + c0 + tx];
    __syncthreads();
    #pragma unroll
    for (int i = ty; i < 32; i += 8)
        outb[(size_t)(c0 + i) * R + r0 + tx] = f2bf(t[tx][i]);
}

// ---------- shared MFMA GEMM core (R6/m97 structure): C[128x128] += A*Bt, K=1024 ----
__device__ __forceinline__ void gemm_core(const short* __restrict__ A,
                                          const short* __restrict__ Bt,
                                          int m0, int n0,
                                          short* As, short* Bs,
                                          float4v acc[4][4]) {
    const int tid = threadIdx.x;
    const int lane = tid & 63, w = tid >> 6;
    const int wr = (w >> 1) * 64, wc = (w & 1) * 64;
    const int srow = lane >> 2;
    const int scol = (lane & 3) * 8;
    for (int k0 = 0; k0 < 1024; k0 += 32) {
        #pragma unroll
        for (int j = 0; j < 2; ++j) {
            const int ch = 2 * w + j;
            GLD16(A  + (size_t)(m0 + ch * 16 + srow) * 1024 + k0 + scol,
                  As + ch * 512 + lane * 8);
            GLD16(Bt + (size_t)(n0 + ch * 16 + srow) * 1024 + k0 + scol,
                  Bs + ch * 512 + lane * 8);
        }
        __syncthreads();
        short8 a[4], b[4];
        #pragma unroll
        for (int m = 0; m < 4; ++m)
            a[m] = *(const short8*)&As[(wr + m * 16 + (lane & 15)) * 32 + (lane >> 4) * 8];
        #pragma unroll
        for (int n = 0; n < 4; ++n)
            b[n] = *(const short8*)&Bs[(wc + n * 16 + (lane & 15)) * 32 + (lane >> 4) * 8];
        #pragma unroll
        for (int m = 0; m < 4; ++m)
            #pragma unroll
            for (int n = 0; n < 4; ++n)
                acc[m][n] = __builtin_amdgcn_mfma_f32_16x16x32_bf16(a[m], b[n], acc[m][n], 0, 0, 0);
        __syncthreads();
    }
}

// ---------- GEMM1: qkv = xt @ W1t^T; scatter q (pre-scaled), k, v^T ----
__global__ __launch_bounds__(256) void gemm_qkv_mfma(const short* __restrict__ xt,
                                                     const short* __restrict__ W1t,
                                                     short* __restrict__ q,
                                                     short* __restrict__ kk,
                                                     short* __restrict__ vt) {
    __shared__ short As[128 * 32], Bs[128 * 32];
    float4v acc[4][4];
    #pragma unroll
    for (int m = 0; m < 4; ++m)
        #pragma unroll
        for (int n = 0; n < 4; ++n) acc[m][n] = (float4v){0.f, 0.f, 0.f, 0.f};
    const int m0 = blockIdx.y * 128, n0 = blockIdx.x * 128;
    gemm_core(xt, W1t, m0, n0, As, Bs, acc);
    const int lane = threadIdx.x & 63, w = threadIdx.x >> 6;
    const int wr = (w >> 1) * 64, wc = (w & 1) * 64;
    const float qscale = 0.125f * 1.44269504f;   // fold softmax scale*log2(e) into q
    #pragma unroll
    for (int n = 0; n < 4; ++n) {
        const int gcol = n0 + wc + n * 16 + (lane & 15);
        const int which = gcol >> 10, hh = (gcol >> 6) & 15, hd = gcol & 63;
        #pragma unroll
        for (int m = 0; m < 4; ++m) {
            #pragma unroll
            for (int ri = 0; ri < 4; ++ri) {
                const int grow = m0 + wr + m * 16 + (lane >> 4) * 4 + ri;
                const int bb = grow >> 11, ss = grow & (S_ - 1);
                float av = acc[m][n][ri];
                if (which == 0) av *= qscale;
                const short v = f2bf(av);
                if (which == 0)      q [((size_t)(bb * H_ + hh) * S_ + ss) * HD_ + hd] = v;
                else if (which == 1) kk[((size_t)(bb * H_ + hh) * S_ + ss) * HD_ + hd] = v;
                else                 vt[((size_t)(bb * H_ + hh) * HD_ + hd) * S_ + ss] = v;
            }
        }
    }
}

// ---------- Flash attention v4: dual-tile block, 32-row waves ----
// grid (16, 32), 256 thr. Waves: tsel = w>>1 selects tile {qpair, 31-qpair};
// wrow = (w&1)*32. One shared K/V staging stream of max(nkbA,nkbB)=32-qpair layers.
// Tiles are independent (each wave-pair owns its rows) -> no combine step.
__global__ __launch_bounds__(256) void attn_mfma(const short* __restrict__ q,
                                                 const short* __restrict__ k,
                                                 const short* __restrict__ vt,
                                                 short* __restrict__ ao) {
    __shared__ short Ks[2][64 * 64];   // [kv][hd], XOR-swizzled 16B chunks
    __shared__ short Vts[2][64 * 64];  // [hd][kv], XOR-swizzled
    __shared__ short Ps[128 * 64];     // [tile*64+q][kv], XOR-swizzled, wave-private
    __shared__ float sums[128];
    const int tid = threadIdx.x;
    const int lane = tid & 63, w = tid >> 6;
    const int tsel = w >> 1;           // which q-tile of the pair
    const int wrow = (w & 1) * 32;     // wave's 32 rows within its 64-row tile
    const int qpair = blockIdx.x;      // 0..15
    const int bh = blockIdx.y;
    const size_t base = (size_t)bh * S_ * HD_;
    const short* qp = q + base;
    const short* kp = k + base;
    const short* vp = vt + base;       // [64][2048]
    const int bb = bh >> 4, hh = bh & 15;

    const int qt = tsel ? (31 - qpair) : qpair;
    const int q0 = qt * 64;
    const int nkb_w = qt + 1;          // layers this wave computes
    const int nkb_max = 32 - qpair;    // layers the block stages

    // Q fragments: rows q0 + wrow + m*16 + (lane&15), k = ks*32 + (lane>>4)*8
    short8 qf[2][2];
    #pragma unroll
    for (int m = 0; m < 2; ++m)
        #pragma unroll
        for (int ks = 0; ks < 2; ++ks)
            qf[m][ks] = *(const short8*)&qp[(size_t)(q0 + wrow + m * 16 + (lane & 15)) * HD_
                                            + ks * 32 + (lane >> 4) * 8];
    float4v accO[2][4];
    float lsum[2] = {0.f, 0.f};
    #pragma unroll
    for (int m = 0; m < 2; ++m)
        #pragma unroll
        for (int n = 0; n < 4; ++n) accO[m][n] = (float4v){0.f, 0.f, 0.f, 0.f};

    // prologue stage of kv-block 0 into buffer 0 (all 4 waves cooperate)
    #pragma unroll
    for (int j = 0; j < 2; ++j) {
        const int g = (w * 2 + j) * 64 + lane;
        const int r = g >> 3, cs = g & 7;
        const int co = (cs ^ (r & 7)) << 3;
        GLD16(kp + (size_t)r * HD_ + co, &Ks[0][g * 8]);
        GLD16(vp + (size_t)r * S_ + co,  &Vts[0][g * 8]);
    }
    int cur = 0;
    for (int kb = 0; kb < nkb_max; ++kb) {
        __syncthreads();               // stage(cur) complete; prev readers done
        if (kb + 1 < nkb_max) {
            const int kv1 = (kb + 1) * 64;
            #pragma unroll
            for (int j = 0; j < 2; ++j) {
                const int g = (w * 2 + j) * 64 + lane;
                const int r = g >> 3, cs = g & 7;
                const int co = (cs ^ (r & 7)) << 3;
                GLD16(kp + (size_t)(kv1 + r) * HD_ + co, &Ks[cur ^ 1][g * 8]);
                GLD16(vp + (size_t)r * S_ + kv1 + co,    &Vts[cur ^ 1][g * 8]);
            }
        }
        if (kb < nkb_w) {
            const int kv0 = kb * 64;
            // S^T = K Q^T : lane owns ONE q-row, 4 consec kv per acc
            float4v accS[2][4];
            #pragma unroll
            for (int m = 0; m < 2; ++m)
                #pragma unroll
                for (int n = 0; n < 4; ++n) accS[m][n] = (float4v){0.f, 0.f, 0.f, 0.f};
            #pragma unroll
            for (int ks = 0; ks < 2; ++ks) {
                #pragma unroll
                for (int n = 0; n < 4; ++n) {
                    const int rowk = n * 16 + (lane & 15);
                    const int ch = ks * 4 + (lane >> 4);
                    const short8 kf = *(const short8*)&Ks[cur][rowk * 64 + ((ch ^ (rowk & 7)) << 3)];
                    #pragma unroll
                    for (int m = 0; m < 2; ++m)
                        accS[m][n] = __builtin_amdgcn_mfma_f32_16x16x32_bf16(kf, qf[m][ks], accS[m][n], 0, 0, 0);
                }
            }
            // softmax: p = exp2(S') — no max subtraction (1/lsum cancels offset)
            const bool diag = (kb == qt);
            #pragma unroll
            for (int m = 0; m < 2; ++m) {
                const int qg = q0 + wrow + m * 16 + (lane & 15);
                const int prow = tsel * 64 + wrow + m * 16 + (lane & 15);
                #pragma unroll
                for (int n = 0; n < 4; ++n) {
                    const int kvb = kv0 + n * 16 + ((lane >> 4) << 2);
                    float p[4];
                    if (diag) {
                        const int dlim = qg - kvb;
                        #pragma unroll
                        for (int ri = 0; ri < 4; ++ri)
                            p[ri] = (ri <= dlim) ? fast_exp2(accS[m][n][ri]) : 0.f;
                    } else {
                        #pragma unroll
                        for (int ri = 0; ri < 4; ++ri)
                            p[ri] = fast_exp2(accS[m][n][ri]);
                    }
                    lsum[m] += (p[0] + p[1]) + (p[2] + p[3]);
                    const unsigned lo = cvt_pk_bf16(p[0], p[1]);
                    const unsigned hi = cvt_pk_bf16(p[2], p[3]);
                    const int col = n * 16 + ((lane >> 4) << 2);
                    const int ch = col >> 3;
                    const int addr = prow * 64 + ((ch ^ (prow & 7)) << 3) + (col & 7);
                    *(uint2*)&Ps[addr] = (uint2){lo, hi};
                }
            }
            // O += P V (P rows wave-private; in-wave LDS ordering suffices)
            #pragma unroll
            for (int ks = 0; ks < 2; ++ks) {
                short8 pf[2];
                #pragma unroll
                for (int m = 0; m < 2; ++m) {
                    const int prow = tsel * 64 + wrow + m * 16 + (lane & 15);
                    const int ch = ks * 4 + (lane >> 4);
                    pf[m] = *(const short8*)&Ps[prow * 64 + ((ch ^ (prow & 7)) << 3)];
                }
                #pragma unroll
                for (int n = 0; n < 4; ++n) {
                    const int vrow = n * 16 + (lane & 15);
                    const int ch = ks * 4 + (lane >> 4);
                    const short8 vf = *(const short8*)&Vts[cur][vrow * 64 + ((ch ^ (vrow & 7)) << 3)];
                    #pragma unroll
                    for (int m = 0; m < 2; ++m)
                        accO[m][n] = __builtin_amdgcn_mfma_f32_16x16x32_bf16(pf[m], vf, accO[m][n], 0, 0, 0);
                }
            }
        }
        cur ^= 1;
    }
    // row sums: 4 lanes share a q-row -> 2 shuffles; sums rows are wave-private
    #pragma unroll
    for (int m = 0; m < 2; ++m) {
        float t = lsum[m];
        t += __shfl_xor(t, 16);
        t += __shfl_xor(t, 32);
        if (lane < 16) sums[tsel * 64 + wrow + m * 16 + lane] = t;
    }
    #pragma unroll
    for (int m = 0; m < 2; ++m) {
        #pragma unroll
        for (int ri = 0; ri < 4; ++ri) {
            const int lrow = wrow + m * 16 + ((lane >> 4) << 2) + ri;
            const float inv = 1.f / sums[tsel * 64 + lrow];
            const int grow = q0 + lrow;
            #pragma unroll
            for (int n = 0; n < 4; ++n) {
                const int col = hh * 64 + n * 16 + (lane & 15);
                ao[((size_t)(bb * S_ + grow)) * D_ + col] = f2bf(accO[m][n][ri] * inv);
            }
        }
    }
}

// ---------- GEMM2: out(b,d,s) = (W2t @ ao^T) ----
__global__ __launch_bounds__(256) void gemm_out_mfma(const short* __restrict__ W2t,
                                                     const short* __restrict__ ao,
                                                     float* __restrict__ out) {
    __shared__ short As[128 * 32], Bs[128 * 32];
    float4v acc[4][4];
    #pragma unroll
    for (int m = 0; m < 4; ++m)
        #pragma unroll
        for (int n = 0; n < 4; ++n) acc[m][n] = (float4v){0.f, 0.f, 0.f, 0.f};
    const int m0 = blockIdx.y * 128, n0 = blockIdx.x * 128;
    gemm_core(W2t, ao, m0, n0, As, Bs, acc);
    const int lane = threadIdx.x & 63, w = threadIdx.x >> 6;
    const int wr = (w >> 1) * 64, wc = (w & 1) * 64;
    #pragma unroll
    for (int m = 0; m < 4; ++m) {
        #pragma unroll
        for (int ri = 0; ri < 4; ++ri) {
            const int grow = m0 + wr + m * 16 + (lane >> 4) * 4 + ri;   // d index
            #pragma unroll
            for (int n = 0; n < 4; ++n) {
                const int gcol = n0 + wc + n * 16 + (lane & 15);        // b*s index
                const int bb = gcol >> 11, ss = gcol & (S_ - 1);
                out[(size_t)bb * D_ * S_ + (size_t)grow * S_ + ss] = acc[m][n][ri];
            }
        }
    }
}

extern "C" void kernel_launch(void* const* d_in, const int* in_sizes, int n_in,
                              void* d_out, int out_size, void* d_ws, size_t ws_size,
                              hipStream_t stream) {
    const float* x  = (const float*)d_in[0];
    const float* W1 = (const float*)d_in[1];
    const float* W2 = (const float*)d_in[2];
    float* out = (float*)d_out;

    short* xt  = (short*)d_ws;                          // 4096x1024
    short* W1t = xt  + (size_t)M_ * D_;                 // 3072x1024
    short* W2t = W1t + (size_t)D3_ * D_;                // 1024x1024
    short* q   = W2t + (size_t)D_ * D_;                 // (b,h,s,hd), pre-scaled
    short* kk  = q   + (size_t)B_ * H_ * S_ * HD_;
    short* vt  = kk  + (size_t)B_ * H_ * S_ * HD_;      // (b,h,hd,s)
    short* ao  = vt  + (size_t)B_ * H_ * S_ * HD_;      // (b,s,d)

    transpose_cvt<<<dim3(S_ / 32, D_ / 32, B_), dim3(32, 8), 0, stream>>>(x, xt, D_, S_);
    transpose_cvt<<<dim3(D3_ / 32, D_ / 32, 1), dim3(32, 8), 0, stream>>>(W1, W1t, D_, D3_);
    transpose_cvt<<<dim3(D_ / 32, D_ / 32, 1), dim3(32, 8), 0, stream>>>(W2, W2t, D_, D_);
    gemm_qkv_mfma<<<dim3(D3_ / 128, M_ / 128), 256, 0, stream>>>(xt, W1t, q, kk, vt);
    attn_mfma<<<dim3(16, B_ * H_), 256, 0, stream>>>(q, kk, vt, ao);
    gemm_out_mfma<<<dim3(M_ / 128, D_ / 128), 256, 0, stream>>>(W2t, ao, out);
}

// Round 12
// 141.757 us; speedup vs baseline: 1.0247x; 1.0247x over previous
//
#include <hip/hip_runtime.h>
#include <math.h>

// Problem constants (SelfAttention: b=2, d=1024, s=2048, h=16, hd=64)
#define B_  2
#define D_  1024
#define S_  2048
#define H_  16
#define HD_ 64
#define D3_ 3072
#define M_  4096   // B_*S_

typedef __attribute__((ext_vector_type(8))) short short8;
typedef __attribute__((ext_vector_type(4))) float float4v;

__device__ __forceinline__ short f2bf(float f) {
    unsigned u = __builtin_bit_cast(unsigned, f);
    unsigned r = (u + 0x7FFFu + ((u >> 16) & 1u)) >> 16;   // RNE
    return (short)r;
}

__device__ __forceinline__ unsigned cvt_pk_bf16(float lo, float hi) {
    unsigned r;
    asm("v_cvt_pk_bf16_f32 %0, %1, %2" : "=v"(r) : "v"(lo), "v"(hi));
    return r;
}

__device__ __forceinline__ float fast_exp2(float x) {
    float r;
    asm("v_exp_f32 %0, %1" : "=v"(r) : "v"(x));
    return r;
}

#define GLD16(gsrc, ldst)                                                      \
    __builtin_amdgcn_global_load_lds(                                          \
        (const __attribute__((address_space(1))) void*)(gsrc),                 \
        (__attribute__((address_space(3))) void*)(ldst), 16, 0, 0)

// ---------- transpose + fp32->bf16 convert: out[z][c][r] = bf16(in[z][r][c]) ----
__global__ __launch_bounds__(256) void transpose_cvt(const float* __restrict__ in,
                                                     short* __restrict__ out,
                                                     int R, int C) {
    __shared__ float t[32][33];
    const int c0 = blockIdx.x * 32, r0 = blockIdx.y * 32;
    const float* inb = in + (size_t)blockIdx.z * R * C;
    short* outb = out + (size_t)blockIdx.z * R * C;
    const int tx = threadIdx.x, ty = threadIdx.y;
    #pragma unroll
    for (int i = ty; i < 32; i += 8)
        t[i][tx] = inb[(size_t)(r0 + i) * C + c0 + tx];
    __syncthreads();
    #pragma unroll
    for (int i = ty; i < 32; i += 8)
        outb[(size_t)(c0 + i) * R + r0 + tx] = f2bf(t[tx][i]);
}

// ---------- shared MFMA GEMM core (R6/m97 structure): C[128x128] += A*Bt, K=1024 ----
__device__ __forceinline__ void gemm_core(const short* __restrict__ A,
                                          const short* __restrict__ Bt,
                                          int m0, int n0,
                                          short* As, short* Bs,
                                          float4v acc[4][4]) {
    const int tid = threadIdx.x;
    const int lane = tid & 63, w = tid >> 6;
    const int wr = (w >> 1) * 64, wc = (w & 1) * 64;
    const int srow = lane >> 2;
    const int scol = (lane & 3) * 8;
    for (int k0 = 0; k0 < 1024; k0 += 32) {
        #pragma unroll
        for (int j = 0; j < 2; ++j) {
            const int ch = 2 * w + j;
            GLD16(A  + (size_t)(m0 + ch * 16 + srow) * 1024 + k0 + scol,
                  As + ch * 512 + lane * 8);
            GLD16(Bt + (size_t)(n0 + ch * 16 + srow) * 1024 + k0 + scol,
                  Bs + ch * 512 + lane * 8);
        }
        __syncthreads();
        short8 a[4], b[4];
        #pragma unroll
        for (int m = 0; m < 4; ++m)
            a[m] = *(const short8*)&As[(wr + m * 16 + (lane & 15)) * 32 + (lane >> 4) * 8];
        #pragma unroll
        for (int n = 0; n < 4; ++n)
            b[n] = *(const short8*)&Bs[(wc + n * 16 + (lane & 15)) * 32 + (lane >> 4) * 8];
        #pragma unroll
        for (int m = 0; m < 4; ++m)
            #pragma unroll
            for (int n = 0; n < 4; ++n)
                acc[m][n] = __builtin_amdgcn_mfma_f32_16x16x32_bf16(a[m], b[n], acc[m][n], 0, 0, 0);
        __syncthreads();
    }
}

// ---------- GEMM1: qkv = xt @ W1t^T; scatter q (pre-scaled), k, v^T ----
__global__ __launch_bounds__(256) void gemm_qkv_mfma(const short* __restrict__ xt,
                                                     const short* __restrict__ W1t,
                                                     short* __restrict__ q,
                                                     short* __restrict__ kk,
                                                     short* __restrict__ vt) {
    __shared__ short As[128 * 32], Bs[128 * 32];
    float4v acc[4][4];
    #pragma unroll
    for (int m = 0; m < 4; ++m)
        #pragma unroll
        for (int n = 0; n < 4; ++n) acc[m][n] = (float4v){0.f, 0.f, 0.f, 0.f};
    const int m0 = blockIdx.y * 128, n0 = blockIdx.x * 128;
    gemm_core(xt, W1t, m0, n0, As, Bs, acc);
    const int lane = threadIdx.x & 63, w = threadIdx.x >> 6;
    const int wr = (w >> 1) * 64, wc = (w & 1) * 64;
    const float qscale = 0.125f * 1.44269504f;   // fold softmax scale*log2(e) into q
    #pragma unroll
    for (int n = 0; n < 4; ++n) {
        const int gcol = n0 + wc + n * 16 + (lane & 15);
        const int which = gcol >> 10, hh = (gcol >> 6) & 15, hd = gcol & 63;
        #pragma unroll
        for (int m = 0; m < 4; ++m) {
            #pragma unroll
            for (int ri = 0; ri < 4; ++ri) {
                const int grow = m0 + wr + m * 16 + (lane >> 4) * 4 + ri;
                const int bb = grow >> 11, ss = grow & (S_ - 1);
                float av = acc[m][n][ri];
                if (which == 0) av *= qscale;
                const short v = f2bf(av);
                if (which == 0)      q [((size_t)(bb * H_ + hh) * S_ + ss) * HD_ + hd] = v;
                else if (which == 1) kk[((size_t)(bb * H_ + hh) * S_ + ss) * HD_ + hd] = v;
                else                 vt[((size_t)(bb * H_ + hh) * HD_ + hd) * S_ + ss] = v;
            }
        }
    }
}

// ---------- Flash attention v5: merged pair, shared staging, all waves both tiles ----
// grid (16, 32), 256 thr, 4 waves x 16 rows. Tiles qtS=qpair, qtL=31-qpair.
// Stage kv stream ONCE (nkbL = 32-qpair layers, covers both tiles since qtS < qtL).
// Every wave computes tile L each layer, plus tile S while kb <= qtS.
__global__ __launch_bounds__(256) void attn_mfma(const short* __restrict__ q,
                                                 const short* __restrict__ k,
                                                 const short* __restrict__ vt,
                                                 short* __restrict__ ao) {
    __shared__ short Ks[2][64 * 64];   // [kv][hd], XOR-swizzled 16B chunks
    __shared__ short Vts[2][64 * 64];  // [hd][kv], XOR-swizzled
    __shared__ short Ps[128 * 64];     // [tile*64+row][kv], wave-private rows
    __shared__ float sums[128];
    const int tid = threadIdx.x;
    const int lane = tid & 63, w = tid >> 6;
    const int qpair = blockIdx.x;      // 0..15
    const int bh = blockIdx.y;
    const size_t base = (size_t)bh * S_ * HD_;
    const short* qp = q + base;
    const short* kp = k + base;
    const short* vp = vt + base;       // [64][2048]
    const int bb = bh >> 4, hh = bh & 15;
    const int wrow = w * 16;           // wave's 16 rows within each 64-row tile

    const int qtS = qpair, qtL = 31 - qpair;
    const int q0S = qtS * 64, q0L = qtL * 64;
    const int nkbL = qtL + 1;          // staged layers; tile S needs first qtS+1 of them

    // Q fragments (16-row fragment per tile): rows q0 + wrow + (lane&15)
    short8 qfS[2], qfL[2];
    #pragma unroll
    for (int ks = 0; ks < 2; ++ks) {
        qfS[ks] = *(const short8*)&qp[(size_t)(q0S + wrow + (lane & 15)) * HD_
                                      + ks * 32 + (lane >> 4) * 8];
        qfL[ks] = *(const short8*)&qp[(size_t)(q0L + wrow + (lane & 15)) * HD_
                                      + ks * 32 + (lane >> 4) * 8];
    }
    float4v accOS[4], accOL[4];
    float lsumS = 0.f, lsumL = 0.f;
    #pragma unroll
    for (int n = 0; n < 4; ++n) {
        accOS[n] = (float4v){0.f, 0.f, 0.f, 0.f};
        accOL[n] = (float4v){0.f, 0.f, 0.f, 0.f};
    }

    // prologue: stage kv-block 0 into buffer 0
    #pragma unroll
    for (int j = 0; j < 2; ++j) {
        const int g = (w * 2 + j) * 64 + lane;
        const int r = g >> 3, cs = g & 7;
        const int co = (cs ^ (r & 7)) << 3;
        GLD16(kp + (size_t)r * HD_ + co, &Ks[0][g * 8]);
        GLD16(vp + (size_t)r * S_ + co,  &Vts[0][g * 8]);
    }
    int cur = 0;
    for (int kb = 0; kb < nkbL; ++kb) {
        const int kv0 = kb * 64;
        __syncthreads();               // stage(cur) complete; prev readers done
        if (kb + 1 < nkbL) {
            const int kv1 = kv0 + 64;
            #pragma unroll
            for (int j = 0; j < 2; ++j) {
                const int g = (w * 2 + j) * 64 + lane;
                const int r = g >> 3, cs = g & 7;
                const int co = (cs ^ (r & 7)) << 3;
                GLD16(kp + (size_t)(kv1 + r) * HD_ + co, &Ks[cur ^ 1][g * 8]);
                GLD16(vp + (size_t)r * S_ + kv1 + co,    &Vts[cur ^ 1][g * 8]);
            }
        }
        const bool actS = (kb <= qtS);
        // S^T = K Q^T for both tiles, sharing each K fragment read
        float4v scS[4], scL[4];
        #pragma unroll
        for (int n = 0; n < 4; ++n) {
            scS[n] = (float4v){0.f, 0.f, 0.f, 0.f};
            scL[n] = (float4v){0.f, 0.f, 0.f, 0.f};
        }
        #pragma unroll
        for (int ks = 0; ks < 2; ++ks) {
            #pragma unroll
            for (int n = 0; n < 4; ++n) {
                const int rowk = n * 16 + (lane & 15);
                const int ch = ks * 4 + (lane >> 4);
                const short8 kf = *(const short8*)&Ks[cur][rowk * 64 + ((ch ^ (rowk & 7)) << 3)];
                scL[n] = __builtin_amdgcn_mfma_f32_16x16x32_bf16(kf, qfL[ks], scL[n], 0, 0, 0);
                if (actS)
                    scS[n] = __builtin_amdgcn_mfma_f32_16x16x32_bf16(kf, qfS[ks], scS[n], 0, 0, 0);
            }
        }
        // softmax tile L (diag only on last layer)
        {
            const bool diag = (kb == qtL);
            const int qg = q0L + wrow + (lane & 15);
            const int prow = 64 + wrow + (lane & 15);
            #pragma unroll
            for (int n = 0; n < 4; ++n) {
                const int kvb = kv0 + n * 16 + ((lane >> 4) << 2);
                float p[4];
                if (diag) {
                    const int dlim = qg - kvb;
                    #pragma unroll
                    for (int ri = 0; ri < 4; ++ri)
                        p[ri] = (ri <= dlim) ? fast_exp2(scL[n][ri]) : 0.f;
                } else {
                    #pragma unroll
                    for (int ri = 0; ri < 4; ++ri)
                        p[ri] = fast_exp2(scL[n][ri]);
                }
                lsumL += (p[0] + p[1]) + (p[2] + p[3]);
                const unsigned lo = cvt_pk_bf16(p[0], p[1]);
                const unsigned hi = cvt_pk_bf16(p[2], p[3]);
                const int col = n * 16 + ((lane >> 4) << 2);
                const int ch = col >> 3;
                const int addr = prow * 64 + ((ch ^ (prow & 7)) << 3) + (col & 7);
                *(uint2*)&Ps[addr] = (uint2){lo, hi};
            }
        }
        // softmax tile S (active layers only; diag at kb == qtS)
        if (actS) {
            const bool diag = (kb == qtS);
            const int qg = q0S + wrow + (lane & 15);
            const int prow = wrow + (lane & 15);
            #pragma unroll
            for (int n = 0; n < 4; ++n) {
                const int kvb = kv0 + n * 16 + ((lane >> 4) << 2);
                float p[4];
                if (diag) {
                    const int dlim = qg - kvb;
                    #pragma unroll
                    for (int ri = 0; ri < 4; ++ri)
                        p[ri] = (ri <= dlim) ? fast_exp2(scS[n][ri]) : 0.f;
                } else {
                    #pragma unroll
                    for (int ri = 0; ri < 4; ++ri)
                        p[ri] = fast_exp2(scS[n][ri]);
                }
                lsumS += (p[0] + p[1]) + (p[2] + p[3]);
                const unsigned lo = cvt_pk_bf16(p[0], p[1]);
                const unsigned hi = cvt_pk_bf16(p[2], p[3]);
                const int col = n * 16 + ((lane >> 4) << 2);
                const int ch = col >> 3;
                const int addr = prow * 64 + ((ch ^ (prow & 7)) << 3) + (col & 7);
                *(uint2*)&Ps[addr] = (uint2){lo, hi};
            }
        }
        // O += P V for both tiles, sharing each V fragment read
        #pragma unroll
        for (int ks = 0; ks < 2; ++ks) {
            const int chp = ks * 4 + (lane >> 4);
            const int prowL = 64 + wrow + (lane & 15);
            const short8 pfL = *(const short8*)&Ps[prowL * 64 + ((chp ^ (prowL & 7)) << 3)];
            short8 pfS;
            if (actS) {
                const int prowS = wrow + (lane & 15);
                pfS = *(const short8*)&Ps[prowS * 64 + ((chp ^ (prowS & 7)) << 3)];
            }
            #pragma unroll
            for (int n = 0; n < 4; ++n) {
                const int vrow = n * 16 + (lane & 15);
                const int ch = ks * 4 + (lane >> 4);
                const short8 vf = *(const short8*)&Vts[cur][vrow * 64 + ((ch ^ (vrow & 7)) << 3)];
                accOL[n] = __builtin_amdgcn_mfma_f32_16x16x32_bf16(pfL, vf, accOL[n], 0, 0, 0);
                if (actS)
                    accOS[n] = __builtin_amdgcn_mfma_f32_16x16x32_bf16(pfS, vf, accOS[n], 0, 0, 0);
            }
        }
        cur ^= 1;
    }
    // row sums: 4 lanes share a q-row -> 2 shuffles; sums rows are wave-private
    {
        float t = lsumS;
        t += __shfl_xor(t, 16);
        t += __shfl_xor(t, 32);
        if (lane < 16) sums[wrow + lane] = t;
    }
    {
        float t = lsumL;
        t += __shfl_xor(t, 16);
        t += __shfl_xor(t, 32);
        if (lane < 16) sums[64 + wrow + lane] = t;
    }
    #pragma unroll
    for (int ri = 0; ri < 4; ++ri) {
        const int lrow = wrow + ((lane >> 4) << 2) + ri;
        const float invS = 1.f / sums[lrow];
        const float invL = 1.f / sums[64 + lrow];
        const int growS = q0S + lrow;
        const int growL = q0L + lrow;
        #pragma unroll
        for (int n = 0; n < 4; ++n) {
            const int col = hh * 64 + n * 16 + (lane & 15);
            ao[((size_t)(bb * S_ + growS)) * D_ + col] = f2bf(accOS[n][ri] * invS);
            ao[((size_t)(bb * S_ + growL)) * D_ + col] = f2bf(accOL[n][ri] * invL);
        }
    }
}

// ---------- GEMM2: out(b,d,s) = (W2t @ ao^T) ----
__global__ __launch_bounds__(256) void gemm_out_mfma(const short* __restrict__ W2t,
                                                     const short* __restrict__ ao,
                                                     float* __restrict__ out) {
    __shared__ short As[128 * 32], Bs[128 * 32];
    float4v acc[4][4];
    #pragma unroll
    for (int m = 0; m < 4; ++m)
        #pragma unroll
        for (int n = 0; n < 4; ++n) acc[m][n] = (float4v){0.f, 0.f, 0.f, 0.f};
    const int m0 = blockIdx.y * 128, n0 = blockIdx.x * 128;
    gemm_core(W2t, ao, m0, n0, As, Bs, acc);
    const int lane = threadIdx.x & 63, w = threadIdx.x >> 6;
    const int wr = (w >> 1) * 64, wc = (w & 1) * 64;
    #pragma unroll
    for (int m = 0; m < 4; ++m) {
        #pragma unroll
        for (int ri = 0; ri < 4; ++ri) {
            const int grow = m0 + wr + m * 16 + (lane >> 4) * 4 + ri;   // d index
            #pragma unroll
            for (int n = 0; n < 4; ++n) {
                const int gcol = n0 + wc + n * 16 + (lane & 15);        // b*s index
                const int bb = gcol >> 11, ss = gcol & (S_ - 1);
                out[(size_t)bb * D_ * S_ + (size_t)grow * S_ + ss] = acc[m][n][ri];
            }
        }
    }
}

extern "C" void kernel_launch(void* const* d_in, const int* in_sizes, int n_in,
                              void* d_out, int out_size, void* d_ws, size_t ws_size,
                              hipStream_t stream) {
    const float* x  = (const float*)d_in[0];
    const float* W1 = (const float*)d_in[1];
    const float* W2 = (const float*)d_in[2];
    float* out = (float*)d_out;

    short* xt  = (short*)d_ws;                          // 4096x1024
    short* W1t = xt  + (size_t)M_ * D_;                 // 3072x1024
    short* W2t = W1t + (size_t)D3_ * D_;                // 1024x1024
    short* q   = W2t + (size_t)D_ * D_;                 // (b,h,s,hd), pre-scaled
    short* kk  = q   + (size_t)B_ * H_ * S_ * HD_;
    short* vt  = kk  + (size_t)B_ * H_ * S_ * HD_;      // (b,h,hd,s)
    short* ao  = vt  + (size_t)B_ * H_ * S_ * HD_;      // (b,s,d)

    transpose_cvt<<<dim3(S_ / 32, D_ / 32, B_), dim3(32, 8), 0, stream>>>(x, xt, D_, S_);
    transpose_cvt<<<dim3(D3_ / 32, D_ / 32, 1), dim3(32, 8), 0, stream>>>(W1, W1t, D_, D3_);
    transpose_cvt<<<dim3(D_ / 32, D_ / 32, 1), dim3(32, 8), 0, stream>>>(W2, W2t, D_, D_);
    gemm_qkv_mfma<<<dim3(D3_ / 128, M_ / 128), 256, 0, stream>>>(xt, W1t, q, kk, vt);
    attn_mfma<<<dim3(16, B_ * H_), 256, 0, stream>>>(q, kk, vt, ao);
    gemm_out_mfma<<<dim3(M_ / 128, D_ / 128), 256, 0, stream>>>(W2t, ao, out);
}

// Round 13
// 121.168 us; speedup vs baseline: 1.1988x; 1.1699x over previous
//
#include <hip/hip_runtime.h>
#include <math.h>

// Problem constants (SelfAttention: b=2, d=1024, s=2048, h=16, hd=64)
#define B_  2
#define D_  1024
#define S_  2048
#define H_  16
#define HD_ 64
#define D3_ 3072
#define M_  4096   // B_*S_

typedef __attribute__((ext_vector_type(8))) short short8;
typedef __attribute__((ext_vector_type(4))) float float4v;

__device__ __forceinline__ short f2bf(float f) {
    unsigned u = __builtin_bit_cast(unsigned, f);
    unsigned r = (u + 0x7FFFu + ((u >> 16) & 1u)) >> 16;   // RNE
    return (short)r;
}

__device__ __forceinline__ unsigned cvt_pk_bf16(float lo, float hi) {
    unsigned r;
    asm("v_cvt_pk_bf16_f32 %0, %1, %2" : "=v"(r) : "v"(lo), "v"(hi));
    return r;
}

__device__ __forceinline__ float fast_exp2(float x) {
    float r;
    asm("v_exp_f32 %0, %1" : "=v"(r) : "v"(x));
    return r;
}

#define GLD16(gsrc, ldst)                                                      \
    __builtin_amdgcn_global_load_lds(                                          \
        (const __attribute__((address_space(1))) void*)(gsrc),                 \
        (__attribute__((address_space(3))) void*)(ldst), 16, 0, 0)

// ---------- transpose + fp32->bf16 convert: out[z][c][r] = bf16(in[z][r][c]) ----
__global__ __launch_bounds__(256) void transpose_cvt(const float* __restrict__ in,
                                                     short* __restrict__ out,
                                                     int R, int C) {
    __shared__ float t[32][33];
    const int c0 = blockIdx.x * 32, r0 = blockIdx.y * 32;
    const float* inb = in + (size_t)blockIdx.z * R * C;
    short* outb = out + (size_t)blockIdx.z * R * C;
    const int tx = threadIdx.x, ty = threadIdx.y;
    #pragma unroll
    for (int i = ty; i < 32; i += 8)
        t[i][tx] = inb[(size_t)(r0 + i) * C + c0 + tx];
    __syncthreads();
    #pragma unroll
    for (int i = ty; i < 32; i += 8)
        outb[(size_t)(c0 + i) * R + r0 + tx] = f2bf(t[tx][i]);
}

// ---------- shared MFMA GEMM core (m97 structure): C[128x128] += A*Bt, K=1024 ----
__device__ __forceinline__ void gemm_core(const short* __restrict__ A,
                                          const short* __restrict__ Bt,
                                          int m0, int n0,
                                          short* As, short* Bs,
                                          float4v acc[4][4]) {
    const int tid = threadIdx.x;
    const int lane = tid & 63, w = tid >> 6;
    const int wr = (w >> 1) * 64, wc = (w & 1) * 64;
    const int srow = lane >> 2;
    const int scol = (lane & 3) * 8;
    for (int k0 = 0; k0 < 1024; k0 += 32) {
        #pragma unroll
        for (int j = 0; j < 2; ++j) {
            const int ch = 2 * w + j;
            GLD16(A  + (size_t)(m0 + ch * 16 + srow) * 1024 + k0 + scol,
                  As + ch * 512 + lane * 8);
            GLD16(Bt + (size_t)(n0 + ch * 16 + srow) * 1024 + k0 + scol,
                  Bs + ch * 512 + lane * 8);
        }
        __syncthreads();
        short8 a[4], b[4];
        #pragma unroll
        for (int m = 0; m < 4; ++m)
            a[m] = *(const short8*)&As[(wr + m * 16 + (lane & 15)) * 32 + (lane >> 4) * 8];
        #pragma unroll
        for (int n = 0; n < 4; ++n)
            b[n] = *(const short8*)&Bs[(wc + n * 16 + (lane & 15)) * 32 + (lane >> 4) * 8];
        #pragma unroll
        for (int m = 0; m < 4; ++m)
            #pragma unroll
            for (int n = 0; n < 4; ++n)
                acc[m][n] = __builtin_amdgcn_mfma_f32_16x16x32_bf16(a[m], b[n], acc[m][n], 0, 0, 0);
        __syncthreads();
    }
}

// ---------- GEMM1: qkv = xt @ W1t^T; scatter q (pre-scaled), k, v^T ----
__global__ __launch_bounds__(256) void gemm_qkv_mfma(const short* __restrict__ xt,
                                                     const short* __restrict__ W1t,
                                                     short* __restrict__ q,
                                                     short* __restrict__ kk,
                                                     short* __restrict__ vt) {
    __shared__ short As[128 * 32], Bs[128 * 32];
    float4v acc[4][4];
    #pragma unroll
    for (int m = 0; m < 4; ++m)
        #pragma unroll
        for (int n = 0; n < 4; ++n) acc[m][n] = (float4v){0.f, 0.f, 0.f, 0.f};
    const int m0 = blockIdx.y * 128, n0 = blockIdx.x * 128;
    gemm_core(xt, W1t, m0, n0, As, Bs, acc);
    const int lane = threadIdx.x & 63, w = threadIdx.x >> 6;
    const int wr = (w >> 1) * 64, wc = (w & 1) * 64;
    const float qscale = 0.125f * 1.44269504f;   // fold softmax scale*log2(e) into q
    #pragma unroll
    for (int n = 0; n < 4; ++n) {
        const int gcol = n0 + wc + n * 16 + (lane & 15);
        const int which = gcol >> 10, hh = (gcol >> 6) & 15, hd = gcol & 63;
        #pragma unroll
        for (int m = 0; m < 4; ++m) {
            #pragma unroll
            for (int ri = 0; ri < 4; ++ri) {
                const int grow = m0 + wr + m * 16 + (lane >> 4) * 4 + ri;
                const int bb = grow >> 11, ss = grow & (S_ - 1);
                float av = acc[m][n][ri];
                if (which == 0) av *= qscale;
                const short v = f2bf(av);
                if (which == 0)      q [((size_t)(bb * H_ + hh) * S_ + ss) * HD_ + hd] = v;
                else if (which == 1) kk[((size_t)(bb * H_ + hh) * S_ + ss) * HD_ + hd] = v;
                else                 vt[((size_t)(bb * H_ + hh) * HD_ + hd) * S_ + ss] = v;
            }
        }
    }
}

// ---------- Flash attention (R5 structure) + bh->XCD pinning (verified in R9/R10) ----
// grid 512 1-D. xcd = bid&7 owns heads 4*xcd..4*xcd+3 (2 MB K/V resident in its L2).
// Block: 64-row q-tiles, uniform pairing qt={qpair, 31-qpair} -> 33 kv-iters each.
__global__ __launch_bounds__(256) void attn_mfma(const short* __restrict__ q,
                                                 const short* __restrict__ k,
                                                 const short* __restrict__ vt,
                                                 short* __restrict__ ao) {
    __shared__ short Ks[2][64 * 64];   // [kv][hd], XOR-swizzled 16B chunks
    __shared__ short Vts[2][64 * 64];  // [hd][kv], XOR-swizzled
    __shared__ short Ps[64 * 64];      // [q][kv], XOR-swizzled, wave-private rows
    __shared__ float sums[64];
    const int tid = threadIdx.x;
    const int lane = tid & 63, w = tid >> 6;
    const int bid = (int)blockIdx.x;
    const int xcd = bid & 7, slot = bid >> 3;
    const int bh = xcd * 4 + (slot & 3);     // pin 4 heads per XCD
    const int qpair = slot >> 2;             // 0..15
    const size_t base = (size_t)bh * S_ * HD_;
    const short* qp = q + base;
    const short* kp = k + base;
    const short* vp = vt + base;       // [64][2048]
    const int bb = bh >> 4, hh = bh & 15;
    const int wrow = w * 16;           // wave's 16 q-rows within the 64-row tile

    for (int half = 0; half < 2; ++half) {
        const int qt = (half == 0) ? qpair : 31 - qpair;
        const int q0 = qt * 64;
        short8 qf[2];
        #pragma unroll
        for (int ks = 0; ks < 2; ++ks)
            qf[ks] = *(const short8*)&qp[(size_t)(q0 + wrow + (lane & 15)) * HD_
                                         + ks * 32 + (lane >> 4) * 8];
        float4v accO[4];
        float lsum = 0.f;
        #pragma unroll
        for (int n = 0; n < 4; ++n) accO[n] = (float4v){0.f, 0.f, 0.f, 0.f};

        const int nkb = qt + 1;
        __syncthreads();                  // prior-half readers of K/V buffers done
        // prologue stage of kv-block 0 into buffer 0
        #pragma unroll
        for (int j = 0; j < 2; ++j) {
            const int g = (w * 2 + j) * 64 + lane;
            const int r = g >> 3, cs = g & 7;
            const int co = (cs ^ (r & 7)) << 3;
            GLD16(kp + (size_t)r * HD_ + co, &Ks[0][g * 8]);
            GLD16(vp + (size_t)r * S_ + co,  &Vts[0][g * 8]);
        }
        int cur = 0;
        for (int kb = 0; kb < nkb; ++kb) {
            const int kv0 = kb * 64;
            __syncthreads();              // stage(cur) complete; prev readers done
            if (kb + 1 < nkb) {
                const int kv1 = kv0 + 64;
                #pragma unroll
                for (int j = 0; j < 2; ++j) {
                    const int g = (w * 2 + j) * 64 + lane;
                    const int r = g >> 3, cs = g & 7;
                    const int co = (cs ^ (r & 7)) << 3;
                    GLD16(kp + (size_t)(kv1 + r) * HD_ + co, &Ks[cur ^ 1][g * 8]);
                    GLD16(vp + (size_t)r * S_ + kv1 + co,    &Vts[cur ^ 1][g * 8]);
                }
            }
            // S^T = K Q^T : lane owns ONE q-row (lane&15), 4 consec kv per acc
            float4v accS[4];
            #pragma unroll
            for (int n = 0; n < 4; ++n) accS[n] = (float4v){0.f, 0.f, 0.f, 0.f};
            #pragma unroll
            for (int ks = 0; ks < 2; ++ks) {
                #pragma unroll
                for (int n = 0; n < 4; ++n) {
                    const int rowk = n * 16 + (lane & 15);
                    const int ch = ks * 4 + (lane >> 4);
                    const short8 kf = *(const short8*)&Ks[cur][rowk * 64 + ((ch ^ (rowk & 7)) << 3)];
                    accS[n] = __builtin_amdgcn_mfma_f32_16x16x32_bf16(kf, qf[ks], accS[n], 0, 0, 0);
                }
            }
            // softmax: p = exp2(S') — no max subtraction (1/lsum cancels offset)
            const bool diag = (kb == qt);
            const int qg = q0 + wrow + (lane & 15);
            const int prow = wrow + (lane & 15);
            #pragma unroll
            for (int n = 0; n < 4; ++n) {
                const int kvb = kv0 + n * 16 + ((lane >> 4) << 2);
                float p[4];
                if (diag) {
                    const int dlim = qg - kvb;
                    #pragma unroll
                    for (int ri = 0; ri < 4; ++ri)
                        p[ri] = (ri <= dlim) ? fast_exp2(accS[n][ri]) : 0.f;
                } else {
                    #pragma unroll
                    for (int ri = 0; ri < 4; ++ri)
                        p[ri] = fast_exp2(accS[n][ri]);
                }
                lsum += (p[0] + p[1]) + (p[2] + p[3]);
                const unsigned lo = cvt_pk_bf16(p[0], p[1]);
                const unsigned hi = cvt_pk_bf16(p[2], p[3]);
                const int col = n * 16 + ((lane >> 4) << 2);
                const int ch = col >> 3;
                const int addr = prow * 64 + ((ch ^ (prow & 7)) << 3) + (col & 7);
                *(uint2*)&Ps[addr] = (uint2){lo, hi};
            }
            // O += P V (P rows wave-private; in-wave LDS ordering suffices)
            #pragma unroll
            for (int ks = 0; ks < 2; ++ks) {
                const int prow2 = wrow + (lane & 15);
                const int chp = ks * 4 + (lane >> 4);
                const short8 pf = *(const short8*)&Ps[prow2 * 64 + ((chp ^ (prow2 & 7)) << 3)];
                #pragma unroll
                for (int n = 0; n < 4; ++n) {
                    const int vrow = n * 16 + (lane & 15);
                    const int ch = ks * 4 + (lane >> 4);
                    const short8 vf = *(const short8*)&Vts[cur][vrow * 64 + ((ch ^ (vrow & 7)) << 3)];
                    accO[n] = __builtin_amdgcn_mfma_f32_16x16x32_bf16(pf, vf, accO[n], 0, 0, 0);
                }
            }
            cur ^= 1;
        }
        // row sums: 4 lanes share a q-row -> 2 shuffles, park in LDS (wave-private rows)
        {
            float t = lsum;
            t += __shfl_xor(t, 16);
            t += __shfl_xor(t, 32);
            if (lane < 16) sums[wrow + lane] = t;
        }
        #pragma unroll
        for (int ri = 0; ri < 4; ++ri) {
            const int lrow = wrow + ((lane >> 4) << 2) + ri;
            const float inv = 1.f / sums[lrow];
            const int grow = q0 + lrow;
            #pragma unroll
            for (int n = 0; n < 4; ++n) {
                const int col = hh * 64 + n * 16 + (lane & 15);
                ao[((size_t)(bb * S_ + grow)) * D_ + col] = f2bf(accO[n][ri] * inv);
            }
        }
    }
}

// ---------- GEMM2: out(b,d,s) = (W2t @ ao^T) ----
__global__ __launch_bounds__(256) void gemm_out_mfma(const short* __restrict__ W2t,
                                                     const short* __restrict__ ao,
                                                     float* __restrict__ out) {
    __shared__ short As[128 * 32], Bs[128 * 32];
    float4v acc[4][4];
    #pragma unroll
    for (int m = 0; m < 4; ++m)
        #pragma unroll
        for (int n = 0; n < 4; ++n) acc[m][n] = (float4v){0.f, 0.f, 0.f, 0.f};
    const int m0 = blockIdx.y * 128, n0 = blockIdx.x * 128;
    gemm_core(W2t, ao, m0, n0, As, Bs, acc);
    const int lane = threadIdx.x & 63, w = threadIdx.x >> 6;
    const int wr = (w >> 1) * 64, wc = (w & 1) * 64;
    #pragma unroll
    for (int m = 0; m < 4; ++m) {
        #pragma unroll
        for (int ri = 0; ri < 4; ++ri) {
            const int grow = m0 + wr + m * 16 + (lane >> 4) * 4 + ri;   // d index
            #pragma unroll
            for (int n = 0; n < 4; ++n) {
                const int gcol = n0 + wc + n * 16 + (lane & 15);        // b*s index
                const int bb = gcol >> 11, ss = gcol & (S_ - 1);
                out[(size_t)bb * D_ * S_ + (size_t)grow * S_ + ss] = acc[m][n][ri];
            }
        }
    }
}

extern "C" void kernel_launch(void* const* d_in, const int* in_sizes, int n_in,
                              void* d_out, int out_size, void* d_ws, size_t ws_size,
                              hipStream_t stream) {
    const float* x  = (const float*)d_in[0];
    const float* W1 = (const float*)d_in[1];
    const float* W2 = (const float*)d_in[2];
    float* out = (float*)d_out;

    short* xt  = (short*)d_ws;                          // 4096x1024
    short* W1t = xt  + (size_t)M_ * D_;                 // 3072x1024
    short* W2t = W1t + (size_t)D3_ * D_;                // 1024x1024
    short* q   = W2t + (size_t)D_ * D_;                 // (b,h,s,hd), pre-scaled
    short* kk  = q   + (size_t)B_ * H_ * S_ * HD_;
    short* vt  = kk  + (size_t)B_ * H_ * S_ * HD_;      // (b,h,hd,s)
    short* ao  = vt  + (size_t)B_ * H_ * S_ * HD_;      // (b,s,d)

    transpose_cvt<<<dim3(S_ / 32, D_ / 32, B_), dim3(32, 8), 0, stream>>>(x, xt, D_, S_);
    transpose_cvt<<<dim3(D3_ / 32, D_ / 32, 1), dim3(32, 8), 0, stream>>>(W1, W1t, D_, D3_);
    transpose_cvt<<<dim3(D_ / 32, D_ / 32, 1), dim3(32, 8), 0, stream>>>(W2, W2t, D_, D_);
    gemm_qkv_mfma<<<dim3(D3_ / 128, M_ / 128), 256, 0, stream>>>(xt, W1t, q, kk, vt);
    attn_mfma<<<dim3(512), 256, 0, stream>>>(q, kk, vt, ao);
    gemm_out_mfma<<<dim3(M_ / 128, D_ / 128), 256, 0, stream>>>(W2t, ao, out);
}